// Round 1
// baseline (275.623 us; speedup 1.0000x reference)
//
#include <hip/hip_runtime.h>

#define N_NODES 100000
#define N_EDGES 1600000
#define FEAT 128
#define NBUCK 782        // ceil(100000/128) buckets of 128 target nodes
#define BUCK_SHIFT 7
#define BUCK_MASK 127
#define GEMM_BLOCKS 1563 // ceil(100000/64)
#define HIST_EPB 4096
#define HIST_BLOCKS 391  // ceil(1.6M/4096)
#define WT_PITCH 136     // 128 + 8 pad: keeps 16B alignment, balances LDS banks

typedef __attribute__((ext_vector_type(8))) short short8;
typedef __attribute__((ext_vector_type(4))) float f32x4;
typedef __attribute__((ext_vector_type(2))) float f32x2;

__device__ inline unsigned short f2bf(float f) {
    unsigned u = __builtin_bit_cast(unsigned, f);
    unsigned r = (u + 0x7FFFu + ((u >> 16) & 1u)) >> 16;  // RNE
    return (unsigned short)r;
}
__device__ inline float bf2f(unsigned h) {
    unsigned u = h << 16;
    return __builtin_bit_cast(float, u);
}

// ============ fused: MFMA GEMM (yraw = bf16(x@W), unscaled) + bucket histogram ======
// GEMM blocks read x fp32, convert in-register, MFMA vs W staged transposed in LDS.
// Hist blocks (atomic/L2 pipe) co-schedule with GEMM blocks (MFMA/HBM pipe).
__global__ __launch_bounds__(256)
void k_gemm_hist(const float* __restrict__ x, const float* __restrict__ W,
                 unsigned short* __restrict__ yb,
                 const int* __restrict__ col, int* __restrict__ bcnt) {
    int bid = blockIdx.x, tid = threadIdx.x;
    if (bid >= GEMM_BLOCKS) {
        __shared__ int hist[NBUCK];
        for (int i = tid; i < NBUCK; i += 256) hist[i] = 0;
        __syncthreads();
        int e0 = (bid - GEMM_BLOCKS) * HIST_EPB;
        int n = min(HIST_EPB, N_EDGES - e0);
        for (int i = tid * 4; i < n; i += 1024) {
            if (i + 3 < n) {
                int4 c4 = *(const int4*)(col + e0 + i);
                atomicAdd(&hist[c4.x >> BUCK_SHIFT], 1);
                atomicAdd(&hist[c4.y >> BUCK_SHIFT], 1);
                atomicAdd(&hist[c4.z >> BUCK_SHIFT], 1);
                atomicAdd(&hist[c4.w >> BUCK_SHIFT], 1);
            } else {
                for (int j = i; j < n; ++j) atomicAdd(&hist[col[e0 + j] >> BUCK_SHIFT], 1);
            }
        }
        __syncthreads();
        for (int i = tid; i < NBUCK; i += 256) {
            int h = hist[i];
            if (h) atomicAdd(&bcnt[i], h);
        }
        return;
    }

    __shared__ unsigned short Ws[FEAT * WT_PITCH];  // Wt[n][k] = bf16(W[k][n])
    for (int idx = tid; idx < FEAT * FEAT; idx += 256) {
        int k = idx >> 7, n = idx & 127;
        Ws[n * WT_PITCH + k] = f2bf(W[idx]);
    }
    __syncthreads();

    int lane = tid & 63;
    int m = lane & 15, quad = lane >> 4;
    int rowBase = bid * 64 + (tid >> 6) * 16;
    int arow = rowBase + m;
    if (arow >= N_NODES) arow = N_NODES - 1;  // clamp OOB A-reads; stores guarded
    const float* xr = x + (size_t)arow * FEAT + quad * 8;

    f32x4 acc[8];
#pragma unroll
    for (int nt = 0; nt < 8; ++nt) acc[nt] = (f32x4){0.f, 0.f, 0.f, 0.f};

#pragma unroll
    for (int kk = 0; kk < 4; ++kk) {
        float4 xa = *(const float4*)(xr + kk * 32);
        float4 xc = *(const float4*)(xr + kk * 32 + 4);
        short8 a;
        a[0] = (short)f2bf(xa.x); a[1] = (short)f2bf(xa.y);
        a[2] = (short)f2bf(xa.z); a[3] = (short)f2bf(xa.w);
        a[4] = (short)f2bf(xc.x); a[5] = (short)f2bf(xc.y);
        a[6] = (short)f2bf(xc.z); a[7] = (short)f2bf(xc.w);
        const unsigned short* wp = Ws + m * WT_PITCH + kk * 32 + quad * 8;
#pragma unroll
        for (int nt = 0; nt < 8; ++nt) {
            short8 bf = *(const short8*)(wp + nt * 16 * WT_PITCH);
            acc[nt] = __builtin_amdgcn_mfma_f32_16x16x32_bf16(a, bf, acc[nt], 0, 0, 0);
        }
    }

    int r0 = rowBase + quad * 4;  // C/D: col = nt*16 + m, row = quad*4 + r
#pragma unroll
    for (int nt = 0; nt < 8; ++nt) {
        int cc = nt * 16 + m;
#pragma unroll
        for (int r = 0; r < 4; ++r) {
            int rr = r0 + r;
            if (rr < N_NODES) yb[(size_t)rr * FEAT + cc] = f2bf(acc[nt][r]);
        }
    }
}

// ============ exclusive scan over 782 bucket counts (1 block) ======================
__global__ __launch_bounds__(1024)
void k_bscan(const int* __restrict__ bcnt, int* __restrict__ bstarts,
             int* __restrict__ bcursor) {
    __shared__ int s[1024];
    int tid = threadIdx.x;
    int v = (tid < NBUCK) ? bcnt[tid] : 0;
    s[tid] = v;
    __syncthreads();
    for (int off = 1; off < 1024; off <<= 1) {
        int t = (tid >= off) ? s[tid - off] : 0;
        __syncthreads();
        s[tid] += t;
        __syncthreads();
    }
    if (tid < NBUCK) {
        int ex = s[tid] - v;
        bstarts[tid] = ex;
        bcursor[tid] = ex;
    }
    if (tid == NBUCK - 1) bstarts[NBUCK] = s[tid];
}

// ============ bucket scatter: pack (src<<7 | tgt&127) into bucket-ordered ebuf =====
// Write frontier = 782 sequential streams -> ~50KB of hot lines, L2-absorbed.
__global__ __launch_bounds__(256)
void k_bscatter(const int* __restrict__ row, const int* __restrict__ col,
                int* __restrict__ bcursor, unsigned* __restrict__ ebuf) {
    __shared__ int hist[NBUCK];
    __shared__ int gbase[NBUCK];
    int tid = threadIdx.x;
    for (int i = tid; i < NBUCK; i += 256) hist[i] = 0;
    __syncthreads();
    int e0 = blockIdx.x * HIST_EPB;
    int n = min(HIST_EPB, N_EDGES - e0);
    for (int i = tid * 4; i < n; i += 1024) {
        if (i + 3 < n) {
            int4 c4 = *(const int4*)(col + e0 + i);
            atomicAdd(&hist[c4.x >> BUCK_SHIFT], 1);
            atomicAdd(&hist[c4.y >> BUCK_SHIFT], 1);
            atomicAdd(&hist[c4.z >> BUCK_SHIFT], 1);
            atomicAdd(&hist[c4.w >> BUCK_SHIFT], 1);
        } else {
            for (int j = i; j < n; ++j) atomicAdd(&hist[col[e0 + j] >> BUCK_SHIFT], 1);
        }
    }
    __syncthreads();
    for (int i = tid; i < NBUCK; i += 256) {
        int h = hist[i];
        gbase[i] = h ? atomicAdd(&bcursor[i], h) : 0;
    }
    __syncthreads();
    for (int i = tid; i < NBUCK; i += 256) hist[i] = 0;  // reuse as local cursor
    __syncthreads();
    for (int i = tid * 4; i < n; i += 1024) {
        if (i + 3 < n) {
            int4 c4 = *(const int4*)(col + e0 + i);
            int4 r4 = *(const int4*)(row + e0 + i);
            int bk, off;
            bk = c4.x >> BUCK_SHIFT; off = atomicAdd(&hist[bk], 1);
            ebuf[gbase[bk] + off] = ((unsigned)r4.x << BUCK_SHIFT) | (unsigned)(c4.x & BUCK_MASK);
            bk = c4.y >> BUCK_SHIFT; off = atomicAdd(&hist[bk], 1);
            ebuf[gbase[bk] + off] = ((unsigned)r4.y << BUCK_SHIFT) | (unsigned)(c4.y & BUCK_MASK);
            bk = c4.z >> BUCK_SHIFT; off = atomicAdd(&hist[bk], 1);
            ebuf[gbase[bk] + off] = ((unsigned)r4.z << BUCK_SHIFT) | (unsigned)(c4.z & BUCK_MASK);
            bk = c4.w >> BUCK_SHIFT; off = atomicAdd(&hist[bk], 1);
            ebuf[gbase[bk] + off] = ((unsigned)r4.w << BUCK_SHIFT) | (unsigned)(c4.w & BUCK_MASK);
        } else {
            for (int j = i; j < n; ++j) {
                int c = col[e0 + j], r = row[e0 + j];
                int bk = c >> BUCK_SHIFT;
                int off = atomicAdd(&hist[bk], 1);
                ebuf[gbase[bk] + off] = ((unsigned)r << BUCK_SHIFT) | (unsigned)(c & BUCK_MASK);
            }
        }
    }
}

// ============ per-bucket CSR: LDS hist + scan -> starts/dinv, LDS-cursor fill ======
__global__ __launch_bounds__(256)
void k_csr(const unsigned* __restrict__ ebuf, const int* __restrict__ bstarts,
           int* __restrict__ starts, float* __restrict__ dinv,
           int* __restrict__ src_idx) {
    __shared__ int hist[128];
    __shared__ int scan[128];
    __shared__ int cur[128];
    int b = blockIdx.x, tid = threadIdx.x;
    int node0 = b << BUCK_SHIFT;
    int nnodes = min(128, N_NODES - node0);
    if (tid < 128) hist[tid] = 0;
    __syncthreads();
    int e0 = bstarts[b], e1 = bstarts[b + 1];
    int ne = e1 - e0;
    for (int i = tid; i < ne; i += 256) atomicAdd(&hist[ebuf[e0 + i] & BUCK_MASK], 1);
    __syncthreads();
    if (tid < 128) scan[tid] = hist[tid];
    __syncthreads();
    for (int off = 1; off < 128; off <<= 1) {
        int t = 0;
        if (tid < 128 && tid >= off) t = scan[tid - off];
        __syncthreads();
        if (tid < 128) scan[tid] += t;
        __syncthreads();
    }
    if (tid < 128) {
        int ex = scan[tid] - hist[tid];
        cur[tid] = ex;
        if (tid < nnodes) {
            starts[node0 + tid] = e0 + ex;
            dinv[node0 + tid] = rsqrtf((float)(hist[tid] + 1));  // +1 self-loop
        }
    }
    if (b == 0 && tid == 0) starts[N_NODES] = N_EDGES;  // sentinel
    __syncthreads();
    for (int i = tid; i < ne; i += 256) {
        unsigned e = ebuf[e0 + i];
        int pos = atomicAdd(&cur[e & BUCK_MASK], 1);
        src_idx[e0 + pos] = (int)(e >> BUCK_SHIFT);
    }
}

// ============ aggregate: out[i] = b + dinv[i]*(dinv[i]*y[i] + sum dinv[s]*y[s]) ====
// One wave per node: 64 lanes x 2 bf16 feats.
// v2: 16-deep load batching — issue 16 gathers before consuming any, so each node
// pays ~1 memory-latency exposure instead of ~4. cnt is wave-uniform -> the
// `if (t < cnt)` guards are scalar branches; all guarded loads issue back-to-back
// and the consume loop drains vmcnt(15..0). Static indices keep v[]/d[] in VGPRs.
__global__ __launch_bounds__(256)
void k_agg(const unsigned short* __restrict__ yb, const int* __restrict__ starts,
           const int* __restrict__ src_idx, const float* __restrict__ dinv,
           const float* __restrict__ bias, float* __restrict__ out) {
    int node = blockIdx.x * 4 + (threadIdx.x >> 6);
    int lane = threadIdx.x & 63;
    if (node >= N_NODES) return;
    int st = starts[node], en = starts[node + 1];
    float di = dinv[node];
    const unsigned* y1 = (const unsigned*)yb;  // 2 bf16 per uint
    unsigned sv = y1[(size_t)node * 64 + lane];
    float a0 = di * bf2f(sv & 0xFFFFu);
    float a1 = di * bf2f(sv >> 16);
    for (int base = st; base < en; base += 64) {
        int nn = min(64, en - base);
        int src = 0;
        float dvv = 0.f;
        if (lane < nn) {
            src = src_idx[base + lane];
            dvv = dinv[src];
        }
        for (int j0 = 0; j0 < nn; j0 += 16) {
            int cnt = nn - j0;
            if (cnt > 16) cnt = 16;
            unsigned v[16];
            float d[16];
            // issue phase: up to 16 independent gathers in flight
#pragma unroll
            for (int t = 0; t < 16; ++t) {
                if (t < cnt) {
                    int s = __shfl(src, j0 + t);
                    d[t] = __shfl(dvv, j0 + t);
                    v[t] = y1[(size_t)s * 64 + lane];
                }
            }
            // consume phase
#pragma unroll
            for (int t = 0; t < 16; ++t) {
                if (t < cnt) {
                    a0 += d[t] * bf2f(v[t] & 0xFFFFu);
                    a1 += d[t] * bf2f(v[t] >> 16);
                }
            }
        }
    }
    float2 bb = ((const float2*)bias)[lane];
    f32x2 o;
    o.x = bb.x + di * a0;
    o.y = bb.y + di * a1;
    // out is write-only (51.2 MB): nontemporal store keeps yb lines resident in L2
    __builtin_nontemporal_store(o, (f32x2*)out + (size_t)node * 64 + lane);
}

extern "C" void kernel_launch(void* const* d_in, const int* in_sizes, int n_in,
                              void* d_out, int out_size, void* d_ws, size_t ws_size,
                              hipStream_t stream) {
    const float* x = (const float*)d_in[0];
    const float* W = (const float*)d_in[1];
    const float* b = (const float*)d_in[2];
    const int* ei = (const int*)d_in[3];
    const int* row = ei;            // edge_index[0] = source
    const int* col = ei + N_EDGES;  // edge_index[1] = target
    float* out = (float*)d_out;

    char* ws = (char*)d_ws;
    size_t off = 0;
    auto alloc = [&](size_t bytes) -> void* {
        void* p = ws + off;
        off += (bytes + 511) & ~(size_t)511;
        return p;
    };
    int* bcnt          = (int*)alloc((NBUCK + 1) * 4);
    int* bstarts       = (int*)alloc((NBUCK + 1) * 4);
    int* bcursor       = (int*)alloc((NBUCK + 1) * 4);
    int* starts        = (int*)alloc((size_t)(N_NODES + 1) * 4);
    float* dinv        = (float*)alloc((size_t)N_NODES * 4);
    unsigned* ebuf     = (unsigned*)alloc((size_t)N_EDGES * 4);
    int* src_idx       = (int*)alloc((size_t)N_EDGES * 4);
    unsigned short* yb = (unsigned short*)alloc((size_t)N_NODES * FEAT * 2);

    hipMemsetAsync(bcnt, 0, (NBUCK + 1) * 4, stream);

    k_gemm_hist<<<GEMM_BLOCKS + HIST_BLOCKS, 256, 0, stream>>>(x, W, yb, col, bcnt);
    k_bscan<<<1, 1024, 0, stream>>>(bcnt, bstarts, bcursor);
    k_bscatter<<<HIST_BLOCKS, 256, 0, stream>>>(row, col, bcursor, ebuf);
    k_csr<<<NBUCK, 256, 0, stream>>>(ebuf, bstarts, starts, dinv, src_idx);
    k_agg<<<(N_NODES + 3) / 4, 256, 0, stream>>>(yb, starts, src_idx, dinv, b, out);
}

// Round 2
// 233.634 us; speedup vs baseline: 1.1797x; 1.1797x over previous
//
#include <hip/hip_runtime.h>

#define N_NODES 100000
#define N_EDGES 1600000
#define FEAT 128
#define NBUCK 782        // ceil(100000/128) buckets of 128 target nodes
#define BUCK_SHIFT 7
#define BUCK_MASK 127
#define GEMM_BLOCKS 1563 // ceil(100000/64)
#define HIST_EPB 4096
#define HIST_BLOCKS 391  // ceil(1.6M/4096)
#define WT_PITCH 136     // 128 + 8 pad: keeps 16B alignment, balances LDS banks

typedef __attribute__((ext_vector_type(8))) short short8;
typedef __attribute__((ext_vector_type(4))) float f32x4;

__device__ inline unsigned short f2bf(float f) {
    unsigned u = __builtin_bit_cast(unsigned, f);
    unsigned r = (u + 0x7FFFu + ((u >> 16) & 1u)) >> 16;  // RNE
    return (unsigned short)r;
}
__device__ inline float bf2f(unsigned h) {
    unsigned u = h << 16;
    return __builtin_bit_cast(float, u);
}

// ============ fused: MFMA GEMM (yraw = bf16(x@W), unscaled) + bucket histogram ======
// GEMM blocks read x fp32, convert in-register, MFMA vs W staged transposed in LDS.
// Hist blocks (atomic/L2 pipe) co-schedule with GEMM blocks (MFMA/HBM pipe).
__global__ __launch_bounds__(256)
void k_gemm_hist(const float* __restrict__ x, const float* __restrict__ W,
                 unsigned short* __restrict__ yb,
                 const int* __restrict__ col, int* __restrict__ bcnt) {
    int bid = blockIdx.x, tid = threadIdx.x;
    if (bid >= GEMM_BLOCKS) {
        __shared__ int hist[NBUCK];
        for (int i = tid; i < NBUCK; i += 256) hist[i] = 0;
        __syncthreads();
        int e0 = (bid - GEMM_BLOCKS) * HIST_EPB;
        int n = min(HIST_EPB, N_EDGES - e0);
        for (int i = tid * 4; i < n; i += 1024) {
            if (i + 3 < n) {
                int4 c4 = *(const int4*)(col + e0 + i);
                atomicAdd(&hist[c4.x >> BUCK_SHIFT], 1);
                atomicAdd(&hist[c4.y >> BUCK_SHIFT], 1);
                atomicAdd(&hist[c4.z >> BUCK_SHIFT], 1);
                atomicAdd(&hist[c4.w >> BUCK_SHIFT], 1);
            } else {
                for (int j = i; j < n; ++j) atomicAdd(&hist[col[e0 + j] >> BUCK_SHIFT], 1);
            }
        }
        __syncthreads();
        for (int i = tid; i < NBUCK; i += 256) {
            int h = hist[i];
            if (h) atomicAdd(&bcnt[i], h);
        }
        return;
    }

    __shared__ unsigned short Ws[FEAT * WT_PITCH];  // Wt[n][k] = bf16(W[k][n])
    for (int idx = tid; idx < FEAT * FEAT; idx += 256) {
        int k = idx >> 7, n = idx & 127;
        Ws[n * WT_PITCH + k] = f2bf(W[idx]);
    }
    __syncthreads();

    int lane = tid & 63;
    int m = lane & 15, quad = lane >> 4;
    int rowBase = bid * 64 + (tid >> 6) * 16;
    int arow = rowBase + m;
    if (arow >= N_NODES) arow = N_NODES - 1;  // clamp OOB A-reads; stores guarded
    const float* xr = x + (size_t)arow * FEAT + quad * 8;

    f32x4 acc[8];
#pragma unroll
    for (int nt = 0; nt < 8; ++nt) acc[nt] = (f32x4){0.f, 0.f, 0.f, 0.f};

#pragma unroll
    for (int kk = 0; kk < 4; ++kk) {
        float4 xa = *(const float4*)(xr + kk * 32);
        float4 xc = *(const float4*)(xr + kk * 32 + 4);
        short8 a;
        a[0] = (short)f2bf(xa.x); a[1] = (short)f2bf(xa.y);
        a[2] = (short)f2bf(xa.z); a[3] = (short)f2bf(xa.w);
        a[4] = (short)f2bf(xc.x); a[5] = (short)f2bf(xc.y);
        a[6] = (short)f2bf(xc.z); a[7] = (short)f2bf(xc.w);
        const unsigned short* wp = Ws + m * WT_PITCH + kk * 32 + quad * 8;
#pragma unroll
        for (int nt = 0; nt < 8; ++nt) {
            short8 bf = *(const short8*)(wp + nt * 16 * WT_PITCH);
            acc[nt] = __builtin_amdgcn_mfma_f32_16x16x32_bf16(a, bf, acc[nt], 0, 0, 0);
        }
    }

    int r0 = rowBase + quad * 4;  // C/D: col = nt*16 + m, row = quad*4 + r
#pragma unroll
    for (int nt = 0; nt < 8; ++nt) {
        int cc = nt * 16 + m;
#pragma unroll
        for (int r = 0; r < 4; ++r) {
            int rr = r0 + r;
            if (rr < N_NODES) yb[(size_t)rr * FEAT + cc] = f2bf(acc[nt][r]);
        }
    }
}

// ============ exclusive scan over 782 bucket counts (1 block) ======================
__global__ __launch_bounds__(1024)
void k_bscan(const int* __restrict__ bcnt, int* __restrict__ bstarts,
             int* __restrict__ bcursor) {
    __shared__ int s[1024];
    int tid = threadIdx.x;
    int v = (tid < NBUCK) ? bcnt[tid] : 0;
    s[tid] = v;
    __syncthreads();
    for (int off = 1; off < 1024; off <<= 1) {
        int t = (tid >= off) ? s[tid - off] : 0;
        __syncthreads();
        s[tid] += t;
        __syncthreads();
    }
    if (tid < NBUCK) {
        int ex = s[tid] - v;
        bstarts[tid] = ex;
        bcursor[tid] = ex;
    }
    if (tid == NBUCK - 1) bstarts[NBUCK] = s[tid];
}

// ============ bucket scatter: pack (src<<7 | tgt&127) into bucket-ordered ebuf =====
// Write frontier = 782 sequential streams -> ~50KB of hot lines, L2-absorbed.
__global__ __launch_bounds__(256)
void k_bscatter(const int* __restrict__ row, const int* __restrict__ col,
                int* __restrict__ bcursor, unsigned* __restrict__ ebuf) {
    __shared__ int hist[NBUCK];
    __shared__ int gbase[NBUCK];
    int tid = threadIdx.x;
    for (int i = tid; i < NBUCK; i += 256) hist[i] = 0;
    __syncthreads();
    int e0 = blockIdx.x * HIST_EPB;
    int n = min(HIST_EPB, N_EDGES - e0);
    for (int i = tid * 4; i < n; i += 1024) {
        if (i + 3 < n) {
            int4 c4 = *(const int4*)(col + e0 + i);
            atomicAdd(&hist[c4.x >> BUCK_SHIFT], 1);
            atomicAdd(&hist[c4.y >> BUCK_SHIFT], 1);
            atomicAdd(&hist[c4.z >> BUCK_SHIFT], 1);
            atomicAdd(&hist[c4.w >> BUCK_SHIFT], 1);
        } else {
            for (int j = i; j < n; ++j) atomicAdd(&hist[col[e0 + j] >> BUCK_SHIFT], 1);
        }
    }
    __syncthreads();
    for (int i = tid; i < NBUCK; i += 256) {
        int h = hist[i];
        gbase[i] = h ? atomicAdd(&bcursor[i], h) : 0;
    }
    __syncthreads();
    for (int i = tid; i < NBUCK; i += 256) hist[i] = 0;  // reuse as local cursor
    __syncthreads();
    for (int i = tid * 4; i < n; i += 1024) {
        if (i + 3 < n) {
            int4 c4 = *(const int4*)(col + e0 + i);
            int4 r4 = *(const int4*)(row + e0 + i);
            int bk, off;
            bk = c4.x >> BUCK_SHIFT; off = atomicAdd(&hist[bk], 1);
            ebuf[gbase[bk] + off] = ((unsigned)r4.x << BUCK_SHIFT) | (unsigned)(c4.x & BUCK_MASK);
            bk = c4.y >> BUCK_SHIFT; off = atomicAdd(&hist[bk], 1);
            ebuf[gbase[bk] + off] = ((unsigned)r4.y << BUCK_SHIFT) | (unsigned)(c4.y & BUCK_MASK);
            bk = c4.z >> BUCK_SHIFT; off = atomicAdd(&hist[bk], 1);
            ebuf[gbase[bk] + off] = ((unsigned)r4.z << BUCK_SHIFT) | (unsigned)(c4.z & BUCK_MASK);
            bk = c4.w >> BUCK_SHIFT; off = atomicAdd(&hist[bk], 1);
            ebuf[gbase[bk] + off] = ((unsigned)r4.w << BUCK_SHIFT) | (unsigned)(c4.w & BUCK_MASK);
        } else {
            for (int j = i; j < n; ++j) {
                int c = col[e0 + j], r = row[e0 + j];
                int bk = c >> BUCK_SHIFT;
                int off = atomicAdd(&hist[bk], 1);
                ebuf[gbase[bk] + off] = ((unsigned)r << BUCK_SHIFT) | (unsigned)(c & BUCK_MASK);
            }
        }
    }
}

// ============ per-bucket CSR: LDS hist + scan -> starts/dinv, LDS-cursor fill ======
__global__ __launch_bounds__(256)
void k_csr(const unsigned* __restrict__ ebuf, const int* __restrict__ bstarts,
           int* __restrict__ starts, float* __restrict__ dinv,
           int* __restrict__ src_idx) {
    __shared__ int hist[128];
    __shared__ int scan[128];
    __shared__ int cur[128];
    int b = blockIdx.x, tid = threadIdx.x;
    int node0 = b << BUCK_SHIFT;
    int nnodes = min(128, N_NODES - node0);
    if (tid < 128) hist[tid] = 0;
    __syncthreads();
    int e0 = bstarts[b], e1 = bstarts[b + 1];
    int ne = e1 - e0;
    for (int i = tid; i < ne; i += 256) atomicAdd(&hist[ebuf[e0 + i] & BUCK_MASK], 1);
    __syncthreads();
    if (tid < 128) scan[tid] = hist[tid];
    __syncthreads();
    for (int off = 1; off < 128; off <<= 1) {
        int t = 0;
        if (tid < 128 && tid >= off) t = scan[tid - off];
        __syncthreads();
        if (tid < 128) scan[tid] += t;
        __syncthreads();
    }
    if (tid < 128) {
        int ex = scan[tid] - hist[tid];
        cur[tid] = ex;
        if (tid < nnodes) {
            starts[node0 + tid] = e0 + ex;
            dinv[node0 + tid] = rsqrtf((float)(hist[tid] + 1));  // +1 self-loop
        }
    }
    if (b == 0 && tid == 0) starts[N_NODES] = N_EDGES;  // sentinel
    __syncthreads();
    for (int i = tid; i < ne; i += 256) {
        unsigned e = ebuf[e0 + i];
        int pos = atomicAdd(&cur[e & BUCK_MASK], 1);
        src_idx[e0 + pos] = (int)(e >> BUCK_SHIFT);
    }
}

// ============ aggregate: out[i] = b + dinv[i]*(dinv[i]*y[i] + sum dinv[s]*y[s]) ====
// One wave per node: 64 lanes x 2 bf16 feats.
// v3: same structure as the proven v1 (unconditional group bodies), but group
// depth extended 4 -> 16 with 8/4/1 remainder tiers. Tier SELECTION is
// wave-uniform branching (fine); tier BODIES are branch-free so the compiler
// must keep all D loads in flight (v2 post-mortem: per-t guards let it collapse
// the pipeline to depth ~1). d-shuffles live in the consume phase (register-only)
// so only v[D] spans the issue/consume boundary.
#define GATHER_GROUP(D)                                             \
    {                                                               \
        unsigned v[D];                                              \
        _Pragma("unroll")                                           \
        for (int t = 0; t < (D); ++t) {                             \
            int s = __shfl(src, j + t);                             \
            v[t] = y1[(size_t)(unsigned)s * 64 + lane];             \
        }                                                           \
        _Pragma("unroll")                                           \
        for (int t = 0; t < (D); ++t) {                             \
            float d = __shfl(dvv, j + t);                           \
            a0 += d * bf2f(v[t] & 0xFFFFu);                         \
            a1 += d * bf2f(v[t] >> 16);                             \
        }                                                           \
        j += (D);                                                   \
    }

__global__ __launch_bounds__(256)
void k_agg(const unsigned short* __restrict__ yb, const int* __restrict__ starts,
           const int* __restrict__ src_idx, const float* __restrict__ dinv,
           const float* __restrict__ bias, float* __restrict__ out) {
    int node = blockIdx.x * 4 + (threadIdx.x >> 6);
    int lane = threadIdx.x & 63;
    if (node >= N_NODES) return;
    int st = starts[node], en = starts[node + 1];
    float di = dinv[node];
    const unsigned* y1 = (const unsigned*)yb;  // 2 bf16 per uint
    unsigned sv = y1[(size_t)node * 64 + lane];
    float a0 = di * bf2f(sv & 0xFFFFu);
    float a1 = di * bf2f(sv >> 16);
    for (int base = st; base < en; base += 64) {
        int nn = min(64, en - base);
        int src = 0;
        float dvv = 0.f;
        if (lane < nn) {
            src = src_idx[base + lane];
            dvv = dinv[src];
        }
        int j = 0;
        while (j + 16 <= nn) GATHER_GROUP(16)
        if (j + 8 <= nn) GATHER_GROUP(8)
        if (j + 4 <= nn) GATHER_GROUP(4)
        for (; j < nn; ++j) {
            int s = __shfl(src, j);
            float d = __shfl(dvv, j);
            unsigned v = y1[(size_t)(unsigned)s * 64 + lane];
            a0 += d * bf2f(v & 0xFFFFu);
            a1 += d * bf2f(v >> 16);
        }
    }
    float2 bb = ((const float2*)bias)[lane];
    float2 o;
    o.x = bb.x + di * a0;
    o.y = bb.y + di * a1;
    ((float2*)out)[(size_t)node * 64 + lane] = o;
}

extern "C" void kernel_launch(void* const* d_in, const int* in_sizes, int n_in,
                              void* d_out, int out_size, void* d_ws, size_t ws_size,
                              hipStream_t stream) {
    const float* x = (const float*)d_in[0];
    const float* W = (const float*)d_in[1];
    const float* b = (const float*)d_in[2];
    const int* ei = (const int*)d_in[3];
    const int* row = ei;            // edge_index[0] = source
    const int* col = ei + N_EDGES;  // edge_index[1] = target
    float* out = (float*)d_out;

    char* ws = (char*)d_ws;
    size_t off = 0;
    auto alloc = [&](size_t bytes) -> void* {
        void* p = ws + off;
        off += (bytes + 511) & ~(size_t)511;
        return p;
    };
    int* bcnt          = (int*)alloc((NBUCK + 1) * 4);
    int* bstarts       = (int*)alloc((NBUCK + 1) * 4);
    int* bcursor       = (int*)alloc((NBUCK + 1) * 4);
    int* starts        = (int*)alloc((size_t)(N_NODES + 1) * 4);
    float* dinv        = (float*)alloc((size_t)N_NODES * 4);
    unsigned* ebuf     = (unsigned*)alloc((size_t)N_EDGES * 4);
    int* src_idx       = (int*)alloc((size_t)N_EDGES * 4);
    unsigned short* yb = (unsigned short*)alloc((size_t)N_NODES * FEAT * 2);

    hipMemsetAsync(bcnt, 0, (NBUCK + 1) * 4, stream);

    k_gemm_hist<<<GEMM_BLOCKS + HIST_BLOCKS, 256, 0, stream>>>(x, W, yb, col, bcnt);
    k_bscan<<<1, 1024, 0, stream>>>(bcnt, bstarts, bcursor);
    k_bscatter<<<HIST_BLOCKS, 256, 0, stream>>>(row, col, bcursor, ebuf);
    k_csr<<<NBUCK, 256, 0, stream>>>(ebuf, bstarts, starts, dinv, src_idx);
    k_agg<<<(N_NODES + 3) / 4, 256, 0, stream>>>(yb, starts, src_idx, dinv, b, out);
}